// Round 1
// baseline (531.095 us; speedup 1.0000x reference)
//
#include <hip/hip_runtime.h>
#include <hip/hip_bf16.h>
#include <math.h>

// Problem constants (B,C,D,H,W) = (2,64,32,64,96), qk=32
constexpr int Cc = 64, Dd = 32, Hh = 64, Ww = 96, QKd = 32;
constexpr int CSTRIDE = Dd * Hh * Ww;      // 196608, stride between channels
constexpr int BDIM = 256;

// ln(10000)/32 and ln(10000)/64
#define FREQ_QK 0.28782313662425574f
#define FREQ_V  0.14391156831212787f

// LDS layout (bytes), total 61952 <= 64KB -> 2 blocks/CU (123.9KB of 160KB)
//  Qs  [32][96] f32 @ 0       (12288 B)
//  Ks  [32][96] f32 @ 12288   (12288 B)
//  Vs  [64][97] f32 @ 24576   (24832 B)  (pad 97: AV column reads conflict-free)
//  U   @ 49408: union of xs [64][96] bf16 (12288 B, dead after projections)
//               and  Ss [32][97] f32 (12416 B, score chunk)
//  inv_sum [32] f32 @ 61824   (128 B)

__global__ __launch_bounds__(BDIM, 2)
void row_attn_kernel(const float* __restrict__ x,
                     const float* __restrict__ Wq, const float* __restrict__ bq,
                     const float* __restrict__ Wk, const float* __restrict__ bk,
                     const float* __restrict__ Wv, const float* __restrict__ bv,
                     const float* __restrict__ gamma,
                     float* __restrict__ y)
{
    __shared__ __align__(16) unsigned char smem_raw[61952];
    float* Qs = (float*)smem_raw;                        // [32][96]
    float* Ks = (float*)(smem_raw + 12288);              // [32][96]
    float* Vs = (float*)(smem_raw + 24576);              // [64][97]
    __hip_bfloat16* xs = (__hip_bfloat16*)(smem_raw + 49408); // [64][96]
    float* Ss = (float*)(smem_raw + 49408);              // [32][97]
    float* inv_sum = (float*)(smem_raw + 61824);         // [32]

    const int t   = threadIdx.x;
    const int bid = blockIdx.x;
    const int b   = bid / (Dd * Hh);
    const int rem = bid % (Dd * Hh);
    const int d   = rem / Hh;
    const int h   = rem % Hh;
    const int base0 = b * (Cc * CSTRIDE) + d * (Hh * Ww) + h * Ww;

    const float g = gamma[0];

    // ---- P1: stage x tile (64 x 96) into LDS as bf16 ----
#pragma unroll
    for (int k = 0; k < (Cc * Ww) / BDIM; ++k) {
        int idx = t + k * BDIM;
        int c = idx / Ww, w = idx % Ww;
        xs[idx] = __float2bfloat16(x[base0 + c * CSTRIDE + w]);
    }
    __syncthreads();

    const int tw = t & 31;   // 0..31 -> w base
    const int tg = t >> 5;   // 0..7  -> row group

    // ---- P2: Q,K projections + PE.  thread: q in [tg*4, tg*4+4), w in {tw, tw+32, tw+64} ----
    {
        const int q0 = tg * 4;
        float accq[4][3], acck[4][3];
#pragma unroll
        for (int u = 0; u < 4; ++u) {
            float bqv = bq[q0 + u], bkv = bk[q0 + u];
#pragma unroll
            for (int v = 0; v < 3; ++v) { accq[u][v] = bqv; acck[u][v] = bkv; }
        }
        for (int c = 0; c < Cc; ++c) {
            float xv[3];
#pragma unroll
            for (int v = 0; v < 3; ++v) xv[v] = __bfloat162float(xs[c * Ww + tw + v * 32]);
#pragma unroll
            for (int u = 0; u < 4; ++u) {
                float wq = Wq[(q0 + u) * Cc + c];
                float wk = Wk[(q0 + u) * Cc + c];
#pragma unroll
                for (int v = 0; v < 3; ++v) {
                    accq[u][v] = fmaf(wq, xv[v], accq[u][v]);
                    acck[u][v] = fmaf(wk, xv[v], acck[u][v]);
                }
            }
        }
#pragma unroll
        for (int u = 0; u < 4; ++u) {
            int q = q0 + u;
            float freq = __expf(-(float)(q & ~1) * FREQ_QK);
#pragma unroll
            for (int v = 0; v < 3; ++v) {
                int w = tw + v * 32;
                float sn, cs;
                __sincosf((float)w * freq, &sn, &cs);
                float pe = (q & 1) ? cs : sn;
                Qs[q * Ww + w] = accq[u][v] + pe;
                Ks[q * Ww + w] = acck[u][v] + pe;
            }
        }
    }

    // ---- P3: V projection + PE.  thread: vc in [tg*8, tg*8+8), same 3 w ----
    {
        const int c0 = tg * 8;
        float accv[8][3];
#pragma unroll
        for (int u = 0; u < 8; ++u) {
            float bvv = bv[c0 + u];
#pragma unroll
            for (int v = 0; v < 3; ++v) accv[u][v] = bvv;
        }
        for (int c = 0; c < Cc; ++c) {
            float xv[3];
#pragma unroll
            for (int v = 0; v < 3; ++v) xv[v] = __bfloat162float(xs[c * Ww + tw + v * 32]);
#pragma unroll
            for (int u = 0; u < 8; ++u) {
                float wv = Wv[(c0 + u) * Cc + c];
#pragma unroll
                for (int v = 0; v < 3; ++v) accv[u][v] = fmaf(wv, xv[v], accv[u][v]);
            }
        }
#pragma unroll
        for (int u = 0; u < 8; ++u) {
            int vc = c0 + u;
            float freq = __expf(-(float)(vc & ~1) * FREQ_V);
#pragma unroll
            for (int v = 0; v < 3; ++v) {
                int w = tw + v * 32;
                float sn, cs;
                __sincosf((float)w * freq, &sn, &cs);
                float pe = (vc & 1) ? cs : sn;
                Vs[vc * 97 + w] = accv[u][v] + pe;
            }
        }
    }
    __syncthreads();  // xs dead from here; Ss may overwrite it

    // ---- chunked attention over i-rows (3 chunks of 32) ----
    for (int ci = 0; ci < 3; ++ci) {
        const int i0 = ci * 32;

        // scores S[il][j] = sum_q Q[q][i0+il] * K[q][j]
        {
            const int il0 = tg * 4;
            float accs[4][3];
#pragma unroll
            for (int u = 0; u < 4; ++u)
#pragma unroll
                for (int v = 0; v < 3; ++v) accs[u][v] = 0.0f;
            for (int q = 0; q < QKd; ++q) {
                float qv[4], kv[3];
#pragma unroll
                for (int u = 0; u < 4; ++u) qv[u] = Qs[q * Ww + i0 + il0 + u];
#pragma unroll
                for (int v = 0; v < 3; ++v) kv[v] = Ks[q * Ww + tw + v * 32];
#pragma unroll
                for (int u = 0; u < 4; ++u)
#pragma unroll
                    for (int v = 0; v < 3; ++v) accs[u][v] = fmaf(qv[u], kv[v], accs[u][v]);
            }
#pragma unroll
            for (int u = 0; u < 4; ++u)
#pragma unroll
                for (int v = 0; v < 3; ++v) Ss[(il0 + u) * 97 + tw + v * 32] = accs[u][v];
        }
        __syncthreads();

        // softmax per row (lanes 0..31, one row each)
        if (t < 32) {
            float m = -1e30f;
            for (int j = 0; j < Ww; ++j) m = fmaxf(m, Ss[t * 97 + j]);
            float sum = 0.0f;
            for (int j = 0; j < Ww; ++j) {
                float e = __expf(Ss[t * 97 + j] - m);
                Ss[t * 97 + j] = e;
                sum += e;
            }
            inv_sum[t] = 1.0f / sum;
        }
        __syncthreads();

        // AV + residual writeout. thread: i_local in {2il, 2il+1}, c in [cg*4, cg*4+4)
        {
            const int il = t & 15, cg = t >> 4;
            const int i_l = il * 2, c0 = cg * 4;
            float acc[4][2];
#pragma unroll
            for (int u = 0; u < 4; ++u) { acc[u][0] = 0.0f; acc[u][1] = 0.0f; }
            for (int j = 0; j < Ww; ++j) {
                float e0 = Ss[i_l * 97 + j];
                float e1 = Ss[(i_l + 1) * 97 + j];
#pragma unroll
                for (int u = 0; u < 4; ++u) {
                    float vv = Vs[(c0 + u) * 97 + j];
                    acc[u][0] = fmaf(vv, e0, acc[u][0]);
                    acc[u][1] = fmaf(vv, e1, acc[u][1]);
                }
            }
            float inv0 = inv_sum[i_l], inv1 = inv_sum[i_l + 1];
#pragma unroll
            for (int u = 0; u < 4; ++u) {
#pragma unroll
                for (int v2 = 0; v2 < 2; ++v2) {
                    int c = c0 + u;
                    int gi = base0 + c * CSTRIDE + i0 + i_l + v2;
                    float o = acc[u][v2] * (v2 ? inv1 : inv0);
                    y[gi] = fmaf(g, o, x[gi]);
                }
            }
        }
        __syncthreads();  // protect Ss before next chunk's score writes
    }
}

extern "C" void kernel_launch(void* const* d_in, const int* in_sizes, int n_in,
                              void* d_out, int out_size, void* d_ws, size_t ws_size,
                              hipStream_t stream) {
    const float* x     = (const float*)d_in[0];
    const float* Wq    = (const float*)d_in[1];
    const float* bq    = (const float*)d_in[2];
    const float* Wk    = (const float*)d_in[3];
    const float* bk    = (const float*)d_in[4];
    const float* Wv    = (const float*)d_in[5];
    const float* bv    = (const float*)d_in[6];
    const float* gamma = (const float*)d_in[7];
    float* y = (float*)d_out;

    dim3 grid(2 * 32 * 64);   // one block per (b,d,h)
    row_attn_kernel<<<grid, BDIM, 0, stream>>>(x, Wq, bq, Wk, bk, Wv, bv, gamma, y);
}

// Round 2
// 215.581 us; speedup vs baseline: 2.4636x; 2.4636x over previous
//
#include <hip/hip_runtime.h>
#include <hip/hip_bf16.h>
#include <math.h>

// Problem constants (B,C,D,H,W) = (2,64,32,64,96), qk=32
constexpr int Cc = 64, Dd = 32, Hh = 64, Ww = 96, QKd = 32;
constexpr int CSTRIDE = Dd * Hh * Ww;   // 196608
constexpr int BDIM = 256;               // 4 waves

// ln(10000)/32 and ln(10000)/64
#define FREQ_QK 0.28782313662425574f
#define FREQ_V  0.14391156831212787f

typedef __bf16 bf16_t;
typedef bf16_t bf16x8 __attribute__((ext_vector_type(8)));
typedef bf16_t bf16x4 __attribute__((ext_vector_type(4)));
typedef float  floatx4 __attribute__((ext_vector_type(4)));

// LDS layout (bf16 elements). All row strides are multiples of 8 bf16 (16 B)
// so ds_read_b128 frag loads stay aligned; bank shifts 36/20/52 words give
// <=2-way conflicts on frag reads (free per m136).
//  Xs [96 w][72]   : X^T bf16 (B-operand layout for projections)   6912 el
//  Ps [96 i][104]  : P bf16 (B-operand layout for PV)              9984 el  (union with Xs)
//  Qs [96 w][40]   : Q^T (A-operand layout for S)                  3840 el
//  Ks [96 w][40]   : K^T (B-operand layout for S)                  3840 el
//  Vs [64 c][104]  : V   (A-operand layout for PV)                 6656 el
constexpr int XS_STRIDE = 72;
constexpr int QS_STRIDE = 40;
constexpr int VS_STRIDE = 104;
constexpr int PS_STRIDE = 104;
constexpr int OFF_QS = 9984;
constexpr int OFF_KS = 9984 + 3840;
constexpr int OFF_VS = 9984 + 7680;
constexpr int SMEM_ELEMS = 9984 + 7680 + 6656;  // 24320 el = 48640 B -> 3 blocks/CU

__global__ __launch_bounds__(BDIM, 3)
void row_attn_mfma(const float* __restrict__ x,
                   const float* __restrict__ Wq, const float* __restrict__ bq,
                   const float* __restrict__ Wk, const float* __restrict__ bk,
                   const float* __restrict__ Wv, const float* __restrict__ bv,
                   const float* __restrict__ gamma,
                   float* __restrict__ y)
{
    __shared__ __align__(16) bf16_t smem[SMEM_ELEMS];
    bf16_t* Xs = smem;            // dead after projections
    bf16_t* Ps = smem;            // written in S stage (after Xs last read)
    bf16_t* Qs = smem + OFF_QS;
    bf16_t* Ks = smem + OFF_KS;
    bf16_t* Vs = smem + OFF_VS;

    const int t    = threadIdx.x;
    const int lane = t & 63;
    const int wid  = t >> 6;       // wave id 0..3
    const int l16  = lane & 15;
    const int quad = lane >> 4;    // 0..3

    const int bid = blockIdx.x;
    const int b   = bid / (Dd * Hh);
    const int rem = bid % (Dd * Hh);
    const int d   = rem / Hh;
    const int h   = rem % Hh;
    const int base0 = b * (Cc * CSTRIDE) + d * (Hh * Ww) + h * Ww;

    // ---- stage X^T into LDS as bf16: Xs[w][c] ----
    // thread handles (w, c-pair): two coalesced dword loads, one packed b32 write
#pragma unroll
    for (int k = 0; k < 12; ++k) {
        int idx = t + k * BDIM;          // 0..3071
        int w  = idx % Ww;
        int c  = (idx / Ww) * 2;         // even c
        float v0 = x[base0 + c * CSTRIDE + w];
        float v1 = x[base0 + (c + 1) * CSTRIDE + w];
        unsigned short u0 = __builtin_bit_cast(unsigned short, (bf16_t)v0);
        unsigned short u1 = __builtin_bit_cast(unsigned short, (bf16_t)v1);
        *(unsigned int*)(&Xs[w * XS_STRIDE + c]) = (unsigned)u0 | ((unsigned)u1 << 16);
    }

    // ---- per-wave weight A-fragments (from global fp32, L1/L2-hot) ----
    const float* Wmat = (wid == 0) ? Wq : (wid == 1) ? Wk : Wv;
    const float* bias = (wid == 0) ? bq : (wid == 1) ? bk : bv;
    const float freqc = (wid < 2) ? FREQ_QK : FREQ_V;
    const int   mbase = (wid == 3) ? 32 : 0;

    bf16x8 wfrag[2][2];
#pragma unroll
    for (int mt = 0; mt < 2; ++mt)
#pragma unroll
        for (int kt = 0; kt < 2; ++kt) {
            const float* p = Wmat + (mbase + mt * 16 + l16) * 64 + kt * 32 + quad * 8;
            float4 lo = *(const float4*)p;
            float4 hi = *(const float4*)(p + 4);
            bf16x8 f;
            f[0] = (bf16_t)lo.x; f[1] = (bf16_t)lo.y; f[2] = (bf16_t)lo.z; f[3] = (bf16_t)lo.w;
            f[4] = (bf16_t)hi.x; f[5] = (bf16_t)hi.y; f[6] = (bf16_t)hi.z; f[7] = (bf16_t)hi.w;
            wfrag[mt][kt] = f;
        }
    float biasv[2][4], freq2[2][2];
#pragma unroll
    for (int mt = 0; mt < 2; ++mt) {
#pragma unroll
        for (int r = 0; r < 4; ++r)
            biasv[mt][r] = bias[mbase + mt * 16 + quad * 4 + r];
#pragma unroll
        for (int p2 = 0; p2 < 2; ++p2)
            freq2[mt][p2] = __expf(-(float)(mbase + mt * 16 + quad * 4 + 2 * p2) * freqc);
    }
    __syncthreads();

    // ---- projections: wave0 -> Qs, wave1 -> Ks, waves2/3 -> Vs halves ----
    // D layout: col(n=w)=l16, row(m)=quad*4+r. Bias + sinusoidal PE fused.
    bf16_t* dstQK = (wid == 0) ? Qs : Ks;
#pragma unroll
    for (int nt = 0; nt < 6; ++nt) {
        bf16x8 bfr[2];
#pragma unroll
        for (int kt = 0; kt < 2; ++kt)
            bfr[kt] = *(const bf16x8*)(&Xs[(nt * 16 + l16) * XS_STRIDE + kt * 32 + quad * 8]);
#pragma unroll
        for (int mt = 0; mt < 2; ++mt) {
            floatx4 acc = {0.f, 0.f, 0.f, 0.f};
            acc = __builtin_amdgcn_mfma_f32_16x16x32_bf16(wfrag[mt][0], bfr[0], acc, 0, 0, 0);
            acc = __builtin_amdgcn_mfma_f32_16x16x32_bf16(wfrag[mt][1], bfr[1], acc, 0, 0, 0);
            float wv = (float)(nt * 16 + l16);
            float out[4];
#pragma unroll
            for (int p2 = 0; p2 < 2; ++p2) {
                float sn, cs;
                __sincosf(wv * freq2[mt][p2], &sn, &cs);
                out[2 * p2]     = acc[2 * p2]     + biasv[mt][2 * p2]     + sn;
                out[2 * p2 + 1] = acc[2 * p2 + 1] + biasv[mt][2 * p2 + 1] + cs;
            }
            if (wid < 2) {
                // Q^T/K^T layout: row w, 4 consecutive q -> one b64 write
                bf16x4 pk;
                pk[0] = (bf16_t)out[0]; pk[1] = (bf16_t)out[1];
                pk[2] = (bf16_t)out[2]; pk[3] = (bf16_t)out[3];
                *(bf16x4*)(&dstQK[(nt * 16 + l16) * QS_STRIDE + mt * 16 + quad * 4]) = pk;
            } else {
                // V layout [c][j]: 4 scalar b16 writes
#pragma unroll
                for (int r = 0; r < 4; ++r)
                    Vs[(mbase + mt * 16 + quad * 4 + r) * VS_STRIDE + nt * 16 + l16] = (bf16_t)out[r];
            }
        }
    }
    __syncthreads();

    // ---- S = Q^T K (K-dim = 32, one MFMA per 16x16 tile), softmax in registers ----
    // i-tiles: wave0 {0,1}, wave1 {2,3}, wave2 {4}, wave3 {5}
    const int it0 = (wid < 2) ? wid * 2 : wid + 2;
    const int itc = (wid < 2) ? 2 : 1;
    for (int ii = 0; ii < itc; ++ii) {
        const int it = it0 + ii;
        bf16x8 afr = *(const bf16x8*)(&Qs[(it * 16 + l16) * QS_STRIDE + quad * 8]);
        floatx4 sacc[6];
#pragma unroll
        for (int jt = 0; jt < 6; ++jt) {
            bf16x8 bfr = *(const bf16x8*)(&Ks[(jt * 16 + l16) * QS_STRIDE + quad * 8]);
            floatx4 z = {0.f, 0.f, 0.f, 0.f};
            sacc[jt] = __builtin_amdgcn_mfma_f32_16x16x32_bf16(afr, bfr, z, 0, 0, 0);
        }
        // row i = it*16 + quad*4 + r lives across 16 lanes (fixed quad) x 6 regs
#pragma unroll
        for (int r = 0; r < 4; ++r) {
            float m = sacc[0][r];
#pragma unroll
            for (int jt = 1; jt < 6; ++jt) m = fmaxf(m, sacc[jt][r]);
#pragma unroll
            for (int msk = 1; msk < 16; msk <<= 1) m = fmaxf(m, __shfl_xor(m, msk));
            float e[6], sum = 0.f;
#pragma unroll
            for (int jt = 0; jt < 6; ++jt) { e[jt] = __expf(sacc[jt][r] - m); sum += e[jt]; }
#pragma unroll
            for (int msk = 1; msk < 16; msk <<= 1) sum += __shfl_xor(sum, msk);
            float inv = 1.0f / sum;
            int row = it * 16 + quad * 4 + r;
#pragma unroll
            for (int jt = 0; jt < 6; ++jt)
                Ps[row * PS_STRIDE + jt * 16 + l16] = (bf16_t)(e[jt] * inv);
        }
    }
    __syncthreads();

    // ---- O = V @ P^T : wave handles c-tile = wid; fused gamma*o + x writeout ----
    const float g = gamma[0];
    const int ct = wid;
    bf16x8 vfr[3];
#pragma unroll
    for (int ks = 0; ks < 3; ++ks)
        vfr[ks] = *(const bf16x8*)(&Vs[(ct * 16 + l16) * VS_STRIDE + ks * 32 + quad * 8]);
#pragma unroll
    for (int it = 0; it < 6; ++it) {
        floatx4 acc = {0.f, 0.f, 0.f, 0.f};
#pragma unroll
        for (int ks = 0; ks < 3; ++ks) {
            bf16x8 bfr = *(const bf16x8*)(&Ps[(it * 16 + l16) * PS_STRIDE + ks * 32 + quad * 8]);
            acc = __builtin_amdgcn_mfma_f32_16x16x32_bf16(vfr[ks], bfr, acc, 0, 0, 0);
        }
#pragma unroll
        for (int r = 0; r < 4; ++r) {
            int c  = ct * 16 + quad * 4 + r;
            int gi = base0 + c * CSTRIDE + it * 16 + l16;
            y[gi] = fmaf(g, acc[r], x[gi]);   // exact fp32 residual
        }
    }
}

extern "C" void kernel_launch(void* const* d_in, const int* in_sizes, int n_in,
                              void* d_out, int out_size, void* d_ws, size_t ws_size,
                              hipStream_t stream) {
    const float* x     = (const float*)d_in[0];
    const float* Wq    = (const float*)d_in[1];
    const float* bq    = (const float*)d_in[2];
    const float* Wk    = (const float*)d_in[3];
    const float* bk    = (const float*)d_in[4];
    const float* Wv    = (const float*)d_in[5];
    const float* bv    = (const float*)d_in[6];
    const float* gamma = (const float*)d_in[7];
    float* y = (float*)d_out;

    dim3 grid(2 * 32 * 64);   // one block per (b,d,h)
    row_attn_mfma<<<grid, BDIM, 0, stream>>>(x, Wq, bq, Wk, bk, Wv, bv, gamma, y);
}